// Round 4
// baseline (1911.363 us; speedup 1.0000x reference)
//
#include <hip/hip_runtime.h>
#include <stdint.h>

// Problem constants
#define N_ 8192
#define D_ 1024
#define E_ 8
#define H_ 4096
#define O_ 1024

using f16 = _Float16;
using f16x8 = __attribute__((ext_vector_type(8))) _Float16;
using f32x4 = __attribute__((ext_vector_type(4))) float;

__device__ __forceinline__ f32x4 mfma16(f16x8 a, f16x8 b, f32x4 c) {
  return __builtin_amdgcn_mfma_f32_16x16x32_f16(a, b, c, 0, 0, 0);
}

__device__ __forceinline__ int imin(int a, int b) { return a < b ? a : b; }

// ---------------------------------------------------------------------------
// Elementwise split-cast: fp32 -> (hi f16, lo f16 scaled by 2^11)
// ---------------------------------------------------------------------------
__global__ void splitx_k(const float* __restrict__ in, f16* __restrict__ oh,
                         f16* __restrict__ ol, int n) {
  int i = blockIdx.x * blockDim.x + threadIdx.x;
  if (i >= n) return;
  float v = in[i];
  f16 h = (f16)v;
  oh[i] = h;
  ol[i] = (f16)((v - (float)h) * 2048.0f);
}

// ---------------------------------------------------------------------------
// Transpose-cast: in [B][R][C] fp32 -> out [B][C][R] f16 (+ optional lo plane)
// ---------------------------------------------------------------------------
template <bool SPLIT>
__global__ void tcast_k(const float* __restrict__ in, f16* __restrict__ oh,
                        f16* __restrict__ ol, int R, int C) {
  __shared__ float tile[32][33];
  const int b = blockIdx.z;
  const float* inb = in + (size_t)b * R * C;
  f16* ohb = oh + (size_t)b * R * C;
  f16* olb = SPLIT ? (ol + (size_t)b * R * C) : nullptr;
  const int c0 = blockIdx.x * 32, r0 = blockIdx.y * 32;
  const int tx = threadIdx.x, ty = threadIdx.y;
#pragma unroll
  for (int j = 0; j < 4; j++)
    tile[ty + 8 * j][tx] = inb[(size_t)(r0 + ty + 8 * j) * C + (c0 + tx)];
  __syncthreads();
#pragma unroll
  for (int j = 0; j < 4; j++) {
    float v = tile[tx][ty + 8 * j];
    f16 h = (f16)v;
    size_t oi = (size_t)(c0 + ty + 8 * j) * R + (r0 + tx);
    ohb[oi] = h;
    if constexpr (SPLIT) olb[oi] = (f16)((v - (float)h) * 2048.0f);
  }
}

// ---------------------------------------------------------------------------
// MFMA GEMM: C[M,N] = A[M,K] @ B^T[N,K]   (A,B f16 row-major; B stored [n][k])
// SPLIT: A/B have hi+lo planes (lo scaled 2^11); acc2 holds cross terms.
// MODE: 0 dense rows; 1 gather A rows via rowid (expert GEMM1);
//       2 A rows offset by offs[z] (expert GEMM2).
// OUT:  0 relu -> f16 hi/lo pair; 1 relu -> f32; 2 relu -> f16 (hid, row offs[z]+r);
//       3 (acc+bias) -> f32 store at out_slots[offs[z]+lr] (combine later).
//
// R2 (kept): coalesced k-contiguous staging, XOR-swizzled LDS tiles,
//            SINGLE-buffered k-loop (dbuf rejected twice: occupancy loss
//            outweighs pipeline gain — m99/m100 confirmed here R1/R3).
// R3 (kept): XCD chunked blockIdx swizzle (T1).
// R4: OUT 0/2 epilogue rebuilt: two half-row passes through a 32 KB
//     [64][128] f32 LDS bounce (fits single-buffer LDS), XOR-swizzled
//     (col ^ (row&7)<<2) -> store 2-way (free), read <=4-way; then
//     coalesced f16x8 global stores (full cache lines, no RMW).
// ---------------------------------------------------------------------------
template <bool SPLIT, int MODE, int OUT>
__global__ __launch_bounds__(256, 4) void gemm_k(
    const f16* __restrict__ Ah, const f16* __restrict__ Al,
    const f16* __restrict__ Bh, const f16* __restrict__ Bl, size_t Bstride,
    const float* __restrict__ bias, int biasStride,
    void* __restrict__ out0, void* __restrict__ out1,
    int M, int N, int K,
    const int* __restrict__ cnt, const int* __restrict__ offs,
    const int* __restrict__ rowid) {
  // ---- XCD chunked swizzle (all grids are multiples of 8) ----
  const uint32_t nwg = gridDim.x * gridDim.y * gridDim.z;
  uint32_t hwid = blockIdx.x + gridDim.x * (blockIdx.y + gridDim.y * blockIdx.z);
  uint32_t lg = ((nwg & 7) == 0) ? ((hwid & 7) * (nwg >> 3) + (hwid >> 3)) : hwid;
  const int bX = lg % gridDim.x;
  const uint32_t lg2 = lg / gridDim.x;
  const int bY = lg2 % gridDim.y;
  const int bZ = lg2 / gridDim.y;

  const int z = bZ;
  const int rows = (MODE == 0) ? M : cnt[z];
  const int rowBase = bX * 128;
  if (rowBase >= rows) return;
  const int colBase = bY * 128;
  const int tid = threadIdx.x, wave = tid >> 6, lane = tid & 63;

  constexpr int NT = SPLIT ? 4 : 2;
  __shared__ __align__(16) f16 lds[NT * 8192];  // 32 KB / 64 KB, single-buffered

  const f16* BhZ = Bh + (size_t)z * Bstride;
  const f16* BlZ = SPLIT ? (Bl + (size_t)z * Bstride) : nullptr;

  // staging role: which LDS tile this wave fills
  const int tile_id = SPLIT ? wave : (wave >> 1);
  constexpr int NI = SPLIT ? 16 : 8;            // staging insts per wave
  const int rowHalf = SPLIT ? 0 : (wave & 1) * 64;  // row offset within tile
  const bool isA = tile_id < (SPLIT ? 2 : 1);

  // per-lane staging constants
  const int lrow = lane >> 3;                // row within 8-row group
  const int kc_l = (lane & 7) ^ lrow;        // swizzled k-group this lane loads

  // per-inst row element-offsets (row_index * K), 32-bit (max ~67M)
  uint32_t rb[NI];
  const f16* src;
  if (isA) {
    src = (SPLIT && tile_id == 1) ? Al : Ah;
#pragma unroll
    for (int i = 0; i < NI; ++i) {
      const int ml = rowHalf + i * 8 + lrow;  // row within 128-row tile
      uint32_t gr;
      if (MODE == 0) {
        gr = (uint32_t)(rowBase + ml);
      } else {
        int l0 = imin(rowBase + ml, rows - 1);
        gr = (MODE == 1) ? (uint32_t)rowid[offs[z] + l0]
                         : (uint32_t)(offs[z] + l0);
      }
      rb[i] = gr * (uint32_t)K;
    }
  } else {
    src = (SPLIT && tile_id == 3) ? BlZ : BhZ;
#pragma unroll
    for (int i = 0; i < NI; ++i) {
      const int ml = rowHalf + i * 8 + lrow;
      rb[i] = (uint32_t)(colBase + ml) * (uint32_t)K;
    }
  }

  f32x4 acc[4][4] = {};
  f32x4 acc2[SPLIT ? 4 : 1][SPLIT ? 4 : 1] = {};

  const int wr = wave >> 1, wc = wave & 1, lm = lane & 15, q4 = lane >> 4;
  const int swA = lm & 7;  // m&7 == lm&7 for all fragment rows
  const f16* tA = lds;
  const f16* tAl = lds + 8192;
  const f16* tB = lds + (SPLIT ? 2 : 1) * 8192;
  const f16* tBl = lds + 3 * 8192;

  // this wave's LDS staging base (f16 elems); lane*16B offset applied by HW
  f16* dstBase = lds + (size_t)tile_id * 8192 + (size_t)rowHalf * 64;

  for (int kt = 0; kt < K; kt += 64) {
    if (kt) __syncthreads();
#pragma unroll
    for (int i = 0; i < NI; ++i) {
      const f16* g = src + (size_t)rb[i] + (size_t)kt + kc_l * 8;
      __builtin_amdgcn_global_load_lds(
          (const __attribute__((address_space(1))) void*)g,
          (__attribute__((address_space(3))) void*)(dstBase + i * 512), 16, 0, 0);
    }
    __syncthreads();
#pragma unroll
    for (int s = 0; s < 2; ++s) {
      const int kc = s * 4 + q4;
      const int sw = (kc ^ swA) * 8;  // swizzled 8-elem k-group offset
      f16x8 a_h[4], b_h[4];
      f16x8 a_l[SPLIT ? 4 : 1], b_l[SPLIT ? 4 : 1];
#pragma unroll
      for (int i = 0; i < 4; i++) {
        int m = wr * 64 + i * 16 + lm;
        a_h[i] = *(const f16x8*)(tA + (size_t)m * 64 + sw);
        if constexpr (SPLIT)
          a_l[i] = *(const f16x8*)(tAl + (size_t)m * 64 + sw);
      }
#pragma unroll
      for (int j = 0; j < 4; j++) {
        int n = wc * 64 + j * 16 + lm;
        b_h[j] = *(const f16x8*)(tB + (size_t)n * 64 + sw);
        if constexpr (SPLIT)
          b_l[j] = *(const f16x8*)(tBl + (size_t)n * 64 + sw);
      }
#pragma unroll
      for (int i = 0; i < 4; i++)
#pragma unroll
        for (int j = 0; j < 4; j++) {
          acc[i][j] = mfma16(a_h[i], b_h[j], acc[i][j]);
          if constexpr (SPLIT) {
            acc2[i][j] = mfma16(a_h[i], b_l[j], acc2[i][j]);
            acc2[i][j] = mfma16(a_l[i], b_h[j], acc2[i][j]);
          }
        }
    }
  }

  // ---- epilogue: C/D layout col=lane&15, row=quad*4+reg ----
  if constexpr (OUT == 0 || OUT == 2) {
    // Two half-row passes through a [64][128] f32 bounce (32 KB, fits the
    // single-buffer LDS). XOR swizzle col^((row&7)<<2): store 2-way (free),
    // read contiguous float4 pairs, <=4-way.
    __syncthreads();  // all waves done with LDS k-tiles
    float* lb = (float*)lds;
#pragma unroll
    for (int pass = 0; pass < 2; ++pass) {
      if (wr == pass) {
#pragma unroll
        for (int j = 0; j < 4; j++) {
          const int n = wc * 64 + j * 16 + lm;
          const float bb = bias[(size_t)z * biasStride + colBase + n];
#pragma unroll
          for (int i = 0; i < 4; i++) {
#pragma unroll
            for (int t = 0; t < 4; t++) {
              const int r = i * 16 + q4 * 4 + t;  // 0..63
              float v = acc[i][j][t];
              if constexpr (SPLIT) v += acc2[i][j][t] * (1.0f / 2048.0f);
              v = fmaxf(v + bb, 0.0f);
              lb[r * 128 + (n ^ ((r & 7) << 2))] = v;
            }
          }
        }
      }
      __syncthreads();
      {
        const int rr = tid >> 4;         // 0..15
        const int cc = (tid & 15) * 8;   // 0..120
#pragma unroll
        for (int it = 0; it < 4; ++it) {
          const int r = it * 16 + rr;    // 0..63
          const int X = (r & 7) << 2;
          const float4 v0 = *(const float4*)(lb + r * 128 + (cc ^ X));
          const float4 v1 = *(const float4*)(lb + r * 128 + ((cc + 4) ^ X));
          const float vv[8] = {v0.x, v0.y, v0.z, v0.w, v1.x, v1.y, v1.z, v1.w};
          f16x8 hv, lv;
#pragma unroll
          for (int e = 0; e < 8; e++) {
            float v = vv[e];
            f16 h = (f16)v;
            hv[e] = h;
            if constexpr (OUT == 0) lv[e] = (f16)((v - (float)h) * 2048.0f);
          }
          const int gr = rowBase + pass * 64 + r;
          if constexpr (OUT == 0) {
            *(f16x8*)((f16*)out0 + (size_t)gr * N + colBase + cc) = hv;
            *(f16x8*)((f16*)out1 + (size_t)gr * N + colBase + cc) = lv;
          } else {
            if (gr < rows)
              *(f16x8*)((f16*)out0 +
                        ((size_t)offs[z] + gr) * N + colBase + cc) = hv;
          }
        }
      }
      __syncthreads();
    }
  } else {
#pragma unroll
    for (int j = 0; j < 4; j++) {
      const int n = colBase + wc * 64 + j * 16 + lm;
      const float bb = bias[(size_t)z * biasStride + n];
#pragma unroll
      for (int i = 0; i < 4; i++) {
#pragma unroll
        for (int t = 0; t < 4; t++) {
          const int lr = rowBase + wr * 64 + i * 16 + q4 * 4 + t;
          float v = acc[i][j][t];
          if constexpr (SPLIT) v += acc2[i][j][t] * (1.0f / 2048.0f);
          v += bb;
          if constexpr (OUT == 1) {
            v = fmaxf(v, 0.0f);
            ((float*)out0)[(size_t)lr * N + n] = v;
          } else {
            if (lr < rows) {
              ((float*)out0)[((size_t)offs[z] + lr) * N + n] = v;
            }
          }
        }
      }
    }
  }
}

// ---------------------------------------------------------------------------
// Gate layer 3: logits[N,8] = h2[N,1024] @ G3[1024,8] + g3   (fp32, wave/token)
// ---------------------------------------------------------------------------
__global__ void logits_k(const float* __restrict__ h2, const float* __restrict__ G3,
                         const float* __restrict__ g3, float* __restrict__ logits) {
  const int t = blockIdx.x * 4 + (threadIdx.x >> 6);
  const int lane = threadIdx.x & 63;
  float acc[8] = {};
  const float* row = h2 + (size_t)t * 1024;
  for (int k = lane; k < 1024; k += 64) {
    float hv = row[k];
    const float* g = G3 + (size_t)k * 8;
#pragma unroll
    for (int e = 0; e < 8; e++) acc[e] += hv * g[e];
  }
#pragma unroll
  for (int e = 0; e < 8; e++) {
    float v = acc[e];
    for (int o = 32; o; o >>= 1) v += __shfl_down(v, o);
    if (lane == 0) logits[(size_t)t * 8 + e] = v + g3[e];
  }
}

// ---------------------------------------------------------------------------
// Top-2 + softmax + dense p + per-expert counting
// ---------------------------------------------------------------------------
__global__ void top2_k(const float* __restrict__ logits, float* __restrict__ pdense,
                       int* __restrict__ ti, float* __restrict__ tp,
                       int* __restrict__ cnt) {
  int t = blockIdx.x * blockDim.x + threadIdx.x;
  if (t >= N_) return;
  float v1 = -1e30f, v2 = -1e30f;
  int i1 = 0, i2 = 0;
#pragma unroll
  for (int e = 0; e < 8; e++) {
    float v = logits[(size_t)t * 8 + e];
    if (v > v1) { v2 = v1; i2 = i1; v1 = v; i1 = e; }
    else if (v > v2) { v2 = v; i2 = e; }
  }
  float e2 = expf(v2 - v1);
  float inv = 1.0f / (1.0f + e2);
  float p1 = inv, p2 = e2 * inv;
#pragma unroll
  for (int e = 0; e < 8; e++)
    pdense[(size_t)t * 8 + e] = (e == i1) ? p1 : ((e == i2) ? p2 : 0.0f);
  ti[2 * t] = i1; ti[2 * t + 1] = i2;
  tp[2 * t] = p1; tp[2 * t + 1] = p2;
  atomicAdd(&cnt[i1], 1);
  atomicAdd(&cnt[i2], 1);
}

__global__ void prefix_k(const int* __restrict__ cnt, int* __restrict__ offs,
                         int* __restrict__ cur) {
  if (threadIdx.x == 0 && blockIdx.x == 0) {
    int s = 0;
    for (int e = 0; e < E_; e++) { offs[e] = s; cur[e] = s; s += cnt[e]; }
    offs[E_] = s;
  }
}

__global__ void place_k(const int* __restrict__ ti, int* __restrict__ cur,
                        int* __restrict__ rowid, int* __restrict__ slotof) {
  int t = blockIdx.x * blockDim.x + threadIdx.x;
  if (t >= N_) return;
#pragma unroll
  for (int k = 0; k < 2; k++) {
    int e = ti[2 * t + k];
    int slot = atomicAdd(&cur[e], 1);
    rowid[slot] = t;
    slotof[2 * t + k] = slot;
  }
}

// ---------------------------------------------------------------------------
// Combine: y[t] = p0*out_slots[s0] + p1*out_slots[s1]   (float4, coalesced)
// ---------------------------------------------------------------------------
__global__ void combine_k(const float* __restrict__ out_slots,
                          const int* __restrict__ slotof,
                          const float* __restrict__ tp, float* __restrict__ y) {
  const int t = blockIdx.x;
  const int c = threadIdx.x * 4;
  const int s0 = slotof[2 * t], s1 = slotof[2 * t + 1];
  const float p0 = tp[2 * t], p1 = tp[2 * t + 1];
  const float4 a = *(const float4*)(out_slots + (size_t)s0 * O_ + c);
  const float4 b = *(const float4*)(out_slots + (size_t)s1 * O_ + c);
  float4 r;
  r.x = p0 * a.x + p1 * b.x;
  r.y = p0 * a.y + p1 * b.y;
  r.z = p0 * a.z + p1 * b.z;
  r.w = p0 * a.w + p1 * b.w;
  *(float4*)(y + (size_t)t * O_ + c) = r;
}

// ---------------------------------------------------------------------------
extern "C" void kernel_launch(void* const* d_in, const int* in_sizes, int n_in,
                              void* d_out, int out_size, void* d_ws, size_t ws_size,
                              hipStream_t stream) {
  const float* x  = (const float*)d_in[0];
  const float* W1 = (const float*)d_in[1];
  const float* b1 = (const float*)d_in[2];
  const float* W2 = (const float*)d_in[3];
  const float* b2 = (const float*)d_in[4];
  const float* G1 = (const float*)d_in[5];
  const float* g1 = (const float*)d_in[6];
  const float* G2 = (const float*)d_in[7];
  const float* g2 = (const float*)d_in[8];
  const float* G3 = (const float*)d_in[9];
  const float* g3 = (const float*)d_in[10];

  float* y = (float*)d_out;                       // [N, O]
  float* pdense = y + (size_t)N_ * O_;            // [N, E]

  char* w = (char*)d_ws;
  auto alloc = [&](size_t bytes) -> char* {
    char* p = w;
    w += (bytes + 255) & ~(size_t)255;
    return p;
  };
  f16* xh  = (f16*)alloc((size_t)N_ * D_ * 2);
  f16* xl  = (f16*)alloc((size_t)N_ * D_ * 2);
  f16* G1h = (f16*)alloc((size_t)D_ * H_ * 2);    // [4096][1024]
  f16* G1l = (f16*)alloc((size_t)D_ * H_ * 2);
  f16* G2h = (f16*)alloc((size_t)H_ * D_ * 2);    // [1024][4096]
  f16* G2l = (f16*)alloc((size_t)H_ * D_ * 2);
  f16* W1t = (f16*)alloc((size_t)E_ * D_ * H_ * 2);  // [8][4096][1024]
  f16* W2t = (f16*)alloc((size_t)E_ * H_ * O_ * 2);  // [8][1024][4096]
  f16* h1h = (f16*)alloc((size_t)N_ * H_ * 2);       // reused as out_slots (f32) later
  f16* h1l = (f16*)alloc((size_t)N_ * H_ * 2);
  float* h2 = (float*)alloc((size_t)N_ * D_ * 4);
  float* logits = (float*)alloc((size_t)N_ * E_ * 4);
  int*   ti  = (int*)alloc((size_t)N_ * 2 * 4);
  float* tp  = (float*)alloc((size_t)N_ * 2 * 4);
  int*   cnt = (int*)alloc(64);
  int*   cur = (int*)alloc(64);
  int*   offs = (int*)alloc(64);
  int*   rowid = (int*)alloc((size_t)N_ * 2 * 4);
  int*   slotof = (int*)alloc((size_t)N_ * 2 * 4);
  f16*   hid = (f16*)alloc((size_t)N_ * 2 * H_ * 2);  // [16384][4096]

  // out_slots[16384][1024] f32 (64 MB) reuses h1h (dead after gate GEMM2)
  float* out_slots = (float*)h1h;

  hipMemsetAsync(cnt, 0, 64, stream);

  // conversions
  splitx_k<<<(N_ * D_) / 256, 256, 0, stream>>>(x, xh, xl, N_ * D_);
  tcast_k<true><<<dim3(H_ / 32, D_ / 32, 1), dim3(32, 8), 0, stream>>>(G1, G1h, G1l, D_, H_);
  tcast_k<true><<<dim3(D_ / 32, H_ / 32, 1), dim3(32, 8), 0, stream>>>(G2, G2h, G2l, H_, D_);
  tcast_k<false><<<dim3(H_ / 32, D_ / 32, E_), dim3(32, 8), 0, stream>>>(W1, W1t, nullptr, D_, H_);
  tcast_k<false><<<dim3(O_ / 32, H_ / 32, E_), dim3(32, 8), 0, stream>>>(W2, W2t, nullptr, H_, O_);

  // gate MLP (split f16, fp32-class)
  gemm_k<true, 0, 0><<<dim3(64, 32, 1), 256, 0, stream>>>(
      xh, xl, G1h, G1l, 0, g1, 0, h1h, h1l, N_, H_, D_,
      nullptr, nullptr, nullptr);
  gemm_k<true, 0, 1><<<dim3(64, 8, 1), 256, 0, stream>>>(
      h1h, h1l, G2h, G2l, 0, g2, 0, h2, nullptr, N_, D_, H_,
      nullptr, nullptr, nullptr);
  logits_k<<<N_ / 4, 256, 0, stream>>>(h2, G3, g3, logits);

  // routing
  top2_k<<<N_ / 256, 256, 0, stream>>>(logits, pdense, ti, tp, cnt);
  prefix_k<<<1, 64, 0, stream>>>(cnt, offs, cur);
  place_k<<<N_ / 256, 256, 0, stream>>>(ti, cur, rowid, slotof);

  // expert path (sparse top-2, plain f16)
  gemm_k<false, 1, 2><<<dim3(64, 32, E_), 256, 0, stream>>>(
      xh, nullptr, W1t, nullptr, (size_t)D_ * H_, b1, H_, hid, nullptr,
      N_, H_, D_, cnt, offs, rowid);
  gemm_k<false, 2, 3><<<dim3(64, 8, E_), 256, 0, stream>>>(
      hid, nullptr, W2t, nullptr, (size_t)H_ * O_, b2, O_, out_slots, nullptr,
      N_, O_, H_, cnt, offs, rowid);

  // weighted combine into y
  combine_k<<<N_, 256, 0, stream>>>(out_slots, slotof, tp, y);
}

// Round 5
// 1703.156 us; speedup vs baseline: 1.1222x; 1.1222x over previous
//
#include <hip/hip_runtime.h>
#include <stdint.h>

// Problem constants
#define N_ 8192
#define D_ 1024
#define E_ 8
#define H_ 4096
#define O_ 1024

using f16 = _Float16;
using f16x8 = __attribute__((ext_vector_type(8))) _Float16;
using f32x4 = __attribute__((ext_vector_type(4))) float;

__device__ __forceinline__ f32x4 mfma16(f16x8 a, f16x8 b, f32x4 c) {
  return __builtin_amdgcn_mfma_f32_16x16x32_f16(a, b, c, 0, 0, 0);
}

__device__ __forceinline__ int imin(int a, int b) { return a < b ? a : b; }

// ---------------------------------------------------------------------------
// Elementwise split-cast: fp32 -> (hi f16, lo f16 scaled by 2^11)
// ---------------------------------------------------------------------------
__global__ void splitx_k(const float* __restrict__ in, f16* __restrict__ oh,
                         f16* __restrict__ ol, int n) {
  int i = blockIdx.x * blockDim.x + threadIdx.x;
  if (i >= n) return;
  float v = in[i];
  f16 h = (f16)v;
  oh[i] = h;
  ol[i] = (f16)((v - (float)h) * 2048.0f);
}

// ---------------------------------------------------------------------------
// Transpose-cast: in [B][R][C] fp32 -> out [B][C][R] f16 (+ optional lo plane)
// ---------------------------------------------------------------------------
template <bool SPLIT>
__global__ void tcast_k(const float* __restrict__ in, f16* __restrict__ oh,
                        f16* __restrict__ ol, int R, int C) {
  __shared__ float tile[32][33];
  const int b = blockIdx.z;
  const float* inb = in + (size_t)b * R * C;
  f16* ohb = oh + (size_t)b * R * C;
  f16* olb = SPLIT ? (ol + (size_t)b * R * C) : nullptr;
  const int c0 = blockIdx.x * 32, r0 = blockIdx.y * 32;
  const int tx = threadIdx.x, ty = threadIdx.y;
#pragma unroll
  for (int j = 0; j < 4; j++)
    tile[ty + 8 * j][tx] = inb[(size_t)(r0 + ty + 8 * j) * C + (c0 + tx)];
  __syncthreads();
#pragma unroll
  for (int j = 0; j < 4; j++) {
    float v = tile[tx][ty + 8 * j];
    f16 h = (f16)v;
    size_t oi = (size_t)(c0 + ty + 8 * j) * R + (r0 + tx);
    ohb[oi] = h;
    if constexpr (SPLIT) olb[oi] = (f16)((v - (float)h) * 2048.0f);
  }
}

// ---------------------------------------------------------------------------
// MFMA GEMM: C[M,N] = A[M,K] @ B^T[N,K]   (A,B f16 row-major; B stored [n][k])
// SPLIT: A/B have hi+lo planes (lo scaled 2^11); acc2 holds cross terms.
// MODE: 0 dense rows; 1 gather A rows via rowid (expert GEMM1);
//       2 A rows offset by offs[z] (expert GEMM2).
// OUT:  0 relu -> f16 hi/lo pair; 1 relu -> f32; 2 relu -> f16 (hid, row offs[z]+r);
//       3 (acc+bias) -> f32 store at out_slots[offs[z]+lr] (combine later).
//
// R2 (kept): coalesced k-contiguous staging, XOR-swizzled LDS tiles,
//            SINGLE-buffered k-loop (dbuf rejected twice: occupancy loss
//            outweighs pipeline gain — m99/m100 confirmed here R1/R3).
// R3 (kept): XCD chunked blockIdx swizzle (T1).
// R4 (kept): conflict-free LDS-bounce epilogue (measured 0 conflicts,
//            WRITE_SIZE at ideal).
// R5: - per-variant launch bounds: SPLIT needs ~230 VGPR; LB(256,4)'s
//       128-VGPR cap forced accumulator spills in the SPLIT gate GEMMs
//       (R2/R4 rest ~1520 vs R3's LB2 rest ~1415). SPLIT -> LB 2,
//       non-split -> LB 4.
//     - ALL OUT modes go through the bounce: OUT 1/3 f32 scalar stores
//       were partial-line RMW; now 2x float4 per lane, full lines.
// ---------------------------------------------------------------------------
template <bool SPLIT, int MODE, int OUT>
__global__ __launch_bounds__(256, SPLIT ? 2 : 4) void gemm_k(
    const f16* __restrict__ Ah, const f16* __restrict__ Al,
    const f16* __restrict__ Bh, const f16* __restrict__ Bl, size_t Bstride,
    const float* __restrict__ bias, int biasStride,
    void* __restrict__ out0, void* __restrict__ out1,
    int M, int N, int K,
    const int* __restrict__ cnt, const int* __restrict__ offs,
    const int* __restrict__ rowid) {
  // ---- XCD chunked swizzle (all grids are multiples of 8) ----
  const uint32_t nwg = gridDim.x * gridDim.y * gridDim.z;
  uint32_t hwid = blockIdx.x + gridDim.x * (blockIdx.y + gridDim.y * blockIdx.z);
  uint32_t lg = ((nwg & 7) == 0) ? ((hwid & 7) * (nwg >> 3) + (hwid >> 3)) : hwid;
  const int bX = lg % gridDim.x;
  const uint32_t lg2 = lg / gridDim.x;
  const int bY = lg2 % gridDim.y;
  const int bZ = lg2 / gridDim.y;

  const int z = bZ;
  const int rows = (MODE == 0) ? M : cnt[z];
  const int rowBase = bX * 128;
  if (rowBase >= rows) return;
  const int colBase = bY * 128;
  const int tid = threadIdx.x, wave = tid >> 6, lane = tid & 63;

  constexpr int NT = SPLIT ? 4 : 2;
  __shared__ __align__(16) f16 lds[NT * 8192];  // 32 KB / 64 KB, single-buffered

  const f16* BhZ = Bh + (size_t)z * Bstride;
  const f16* BlZ = SPLIT ? (Bl + (size_t)z * Bstride) : nullptr;

  // staging role: which LDS tile this wave fills
  const int tile_id = SPLIT ? wave : (wave >> 1);
  constexpr int NI = SPLIT ? 16 : 8;            // staging insts per wave
  const int rowHalf = SPLIT ? 0 : (wave & 1) * 64;  // row offset within tile
  const bool isA = tile_id < (SPLIT ? 2 : 1);

  // per-lane staging constants
  const int lrow = lane >> 3;                // row within 8-row group
  const int kc_l = (lane & 7) ^ lrow;        // swizzled k-group this lane loads

  // per-inst row element-offsets (row_index * K), 32-bit (max ~67M)
  uint32_t rb[NI];
  const f16* src;
  if (isA) {
    src = (SPLIT && tile_id == 1) ? Al : Ah;
#pragma unroll
    for (int i = 0; i < NI; ++i) {
      const int ml = rowHalf + i * 8 + lrow;  // row within 128-row tile
      uint32_t gr;
      if (MODE == 0) {
        gr = (uint32_t)(rowBase + ml);
      } else {
        int l0 = imin(rowBase + ml, rows - 1);
        gr = (MODE == 1) ? (uint32_t)rowid[offs[z] + l0]
                         : (uint32_t)(offs[z] + l0);
      }
      rb[i] = gr * (uint32_t)K;
    }
  } else {
    src = (SPLIT && tile_id == 3) ? BlZ : BhZ;
#pragma unroll
    for (int i = 0; i < NI; ++i) {
      const int ml = rowHalf + i * 8 + lrow;
      rb[i] = (uint32_t)(colBase + ml) * (uint32_t)K;
    }
  }

  f32x4 acc[4][4] = {};
  f32x4 acc2[SPLIT ? 4 : 1][SPLIT ? 4 : 1] = {};

  const int wr = wave >> 1, wc = wave & 1, lm = lane & 15, q4 = lane >> 4;
  const int swA = lm & 7;  // m&7 == lm&7 for all fragment rows
  const f16* tA = lds;
  const f16* tAl = lds + 8192;
  const f16* tB = lds + (SPLIT ? 2 : 1) * 8192;
  const f16* tBl = lds + 3 * 8192;

  // this wave's LDS staging base (f16 elems); lane*16B offset applied by HW
  f16* dstBase = lds + (size_t)tile_id * 8192 + (size_t)rowHalf * 64;

  for (int kt = 0; kt < K; kt += 64) {
    if (kt) __syncthreads();
#pragma unroll
    for (int i = 0; i < NI; ++i) {
      const f16* g = src + (size_t)rb[i] + (size_t)kt + kc_l * 8;
      __builtin_amdgcn_global_load_lds(
          (const __attribute__((address_space(1))) void*)g,
          (__attribute__((address_space(3))) void*)(dstBase + i * 512), 16, 0, 0);
    }
    __syncthreads();
#pragma unroll
    for (int s = 0; s < 2; ++s) {
      const int kc = s * 4 + q4;
      const int sw = (kc ^ swA) * 8;  // swizzled 8-elem k-group offset
      f16x8 a_h[4], b_h[4];
      f16x8 a_l[SPLIT ? 4 : 1], b_l[SPLIT ? 4 : 1];
#pragma unroll
      for (int i = 0; i < 4; i++) {
        int m = wr * 64 + i * 16 + lm;
        a_h[i] = *(const f16x8*)(tA + (size_t)m * 64 + sw);
        if constexpr (SPLIT)
          a_l[i] = *(const f16x8*)(tAl + (size_t)m * 64 + sw);
      }
#pragma unroll
      for (int j = 0; j < 4; j++) {
        int n = wc * 64 + j * 16 + lm;
        b_h[j] = *(const f16x8*)(tB + (size_t)n * 64 + sw);
        if constexpr (SPLIT)
          b_l[j] = *(const f16x8*)(tBl + (size_t)n * 64 + sw);
      }
#pragma unroll
      for (int i = 0; i < 4; i++)
#pragma unroll
        for (int j = 0; j < 4; j++) {
          acc[i][j] = mfma16(a_h[i], b_h[j], acc[i][j]);
          if constexpr (SPLIT) {
            acc2[i][j] = mfma16(a_h[i], b_l[j], acc2[i][j]);
            acc2[i][j] = mfma16(a_l[i], b_h[j], acc2[i][j]);
          }
        }
    }
  }

  // ---- epilogue: C/D layout col=lane&15, row=quad*4+reg ----
  // Two half-row passes through a [64][128] f32 bounce (32 KB, fits the
  // single-buffer LDS). XOR swizzle col^((row&7)<<2): store 2-way (free),
  // read <=4-way (measured 0 conflicts in R4). Then coalesced full-line
  // global stores: f16x8 (OUT 0/2) or 2x float4 (OUT 1/3) per lane.
  __syncthreads();  // all waves done with LDS k-tiles
  float* lb = (float*)lds;
#pragma unroll
  for (int pass = 0; pass < 2; ++pass) {
    if (wr == pass) {
#pragma unroll
      for (int j = 0; j < 4; j++) {
        const int n = wc * 64 + j * 16 + lm;
        const float bb = bias[(size_t)z * biasStride + colBase + n];
#pragma unroll
        for (int i = 0; i < 4; i++) {
#pragma unroll
          for (int t = 0; t < 4; t++) {
            const int r = i * 16 + q4 * 4 + t;  // 0..63
            float v = acc[i][j][t];
            if constexpr (SPLIT) v += acc2[i][j][t] * (1.0f / 2048.0f);
            v += bb;
            if constexpr (OUT != 3) v = fmaxf(v, 0.0f);
            lb[r * 128 + (n ^ ((r & 7) << 2))] = v;
          }
        }
      }
    }
    __syncthreads();
    {
      const int rr = tid >> 4;         // 0..15
      const int cc = (tid & 15) * 8;   // 0..120
#pragma unroll
      for (int it = 0; it < 4; ++it) {
        const int r = it * 16 + rr;    // 0..63
        const int X = (r & 7) << 2;
        const float4 v0 = *(const float4*)(lb + r * 128 + (cc ^ X));
        const float4 v1 = *(const float4*)(lb + r * 128 + ((cc + 4) ^ X));
        const int gr = rowBase + pass * 64 + r;
        if constexpr (OUT == 0 || OUT == 2) {
          const float vv[8] = {v0.x, v0.y, v0.z, v0.w, v1.x, v1.y, v1.z, v1.w};
          f16x8 hv, lv;
#pragma unroll
          for (int e = 0; e < 8; e++) {
            float v = vv[e];
            f16 h = (f16)v;
            hv[e] = h;
            if constexpr (OUT == 0) lv[e] = (f16)((v - (float)h) * 2048.0f);
          }
          if constexpr (OUT == 0) {
            *(f16x8*)((f16*)out0 + (size_t)gr * N + colBase + cc) = hv;
            *(f16x8*)((f16*)out1 + (size_t)gr * N + colBase + cc) = lv;
          } else {
            if (gr < rows)
              *(f16x8*)((f16*)out0 +
                        ((size_t)offs[z] + gr) * N + colBase + cc) = hv;
          }
        } else if constexpr (OUT == 1) {
          float* po = (float*)out0 + (size_t)gr * N + colBase + cc;
          *(float4*)po = v0;
          *(float4*)(po + 4) = v1;
        } else {  // OUT == 3
          if (gr < rows) {
            float* po = (float*)out0 + ((size_t)offs[z] + gr) * N + colBase + cc;
            *(float4*)po = v0;
            *(float4*)(po + 4) = v1;
          }
        }
      }
    }
    __syncthreads();
  }
}

// ---------------------------------------------------------------------------
// Gate layer 3: logits[N,8] = h2[N,1024] @ G3[1024,8] + g3   (fp32, wave/token)
// ---------------------------------------------------------------------------
__global__ void logits_k(const float* __restrict__ h2, const float* __restrict__ G3,
                         const float* __restrict__ g3, float* __restrict__ logits) {
  const int t = blockIdx.x * 4 + (threadIdx.x >> 6);
  const int lane = threadIdx.x & 63;
  float acc[8] = {};
  const float* row = h2 + (size_t)t * 1024;
  for (int k = lane; k < 1024; k += 64) {
    float hv = row[k];
    const float* g = G3 + (size_t)k * 8;
#pragma unroll
    for (int e = 0; e < 8; e++) acc[e] += hv * g[e];
  }
#pragma unroll
  for (int e = 0; e < 8; e++) {
    float v = acc[e];
    for (int o = 32; o; o >>= 1) v += __shfl_down(v, o);
    if (lane == 0) logits[(size_t)t * 8 + e] = v + g3[e];
  }
}

// ---------------------------------------------------------------------------
// Top-2 + softmax + dense p + per-expert counting
// ---------------------------------------------------------------------------
__global__ void top2_k(const float* __restrict__ logits, float* __restrict__ pdense,
                       int* __restrict__ ti, float* __restrict__ tp,
                       int* __restrict__ cnt) {
  int t = blockIdx.x * blockDim.x + threadIdx.x;
  if (t >= N_) return;
  float v1 = -1e30f, v2 = -1e30f;
  int i1 = 0, i2 = 0;
#pragma unroll
  for (int e = 0; e < 8; e++) {
    float v = logits[(size_t)t * 8 + e];
    if (v > v1) { v2 = v1; i2 = i1; v1 = v; i1 = e; }
    else if (v > v2) { v2 = v; i2 = e; }
  }
  float e2 = expf(v2 - v1);
  float inv = 1.0f / (1.0f + e2);
  float p1 = inv, p2 = e2 * inv;
#pragma unroll
  for (int e = 0; e < 8; e++)
    pdense[(size_t)t * 8 + e] = (e == i1) ? p1 : ((e == i2) ? p2 : 0.0f);
  ti[2 * t] = i1; ti[2 * t + 1] = i2;
  tp[2 * t] = p1; tp[2 * t + 1] = p2;
  atomicAdd(&cnt[i1], 1);
  atomicAdd(&cnt[i2], 1);
}

__global__ void prefix_k(const int* __restrict__ cnt, int* __restrict__ offs,
                         int* __restrict__ cur) {
  if (threadIdx.x == 0 && blockIdx.x == 0) {
    int s = 0;
    for (int e = 0; e < E_; e++) { offs[e] = s; cur[e] = s; s += cnt[e]; }
    offs[E_] = s;
  }
}

__global__ void place_k(const int* __restrict__ ti, int* __restrict__ cur,
                        int* __restrict__ rowid, int* __restrict__ slotof) {
  int t = blockIdx.x * blockDim.x + threadIdx.x;
  if (t >= N_) return;
#pragma unroll
  for (int k = 0; k < 2; k++) {
    int e = ti[2 * t + k];
    int slot = atomicAdd(&cur[e], 1);
    rowid[slot] = t;
    slotof[2 * t + k] = slot;
  }
}

// ---------------------------------------------------------------------------
// Combine: y[t] = p0*out_slots[s0] + p1*out_slots[s1]   (float4, coalesced)
// ---------------------------------------------------------------------------
__global__ void combine_k(const float* __restrict__ out_slots,
                          const int* __restrict__ slotof,
                          const float* __restrict__ tp, float* __restrict__ y) {
  const int t = blockIdx.x;
  const int c = threadIdx.x * 4;
  const int s0 = slotof[2 * t], s1 = slotof[2 * t + 1];
  const float p0 = tp[2 * t], p1 = tp[2 * t + 1];
  const float4 a = *(const float4*)(out_slots + (size_t)s0 * O_ + c);
  const float4 b = *(const float4*)(out_slots + (size_t)s1 * O_ + c);
  float4 r;
  r.x = p0 * a.x + p1 * b.x;
  r.y = p0 * a.y + p1 * b.y;
  r.z = p0 * a.z + p1 * b.z;
  r.w = p0 * a.w + p1 * b.w;
  *(float4*)(y + (size_t)t * O_ + c) = r;
}

// ---------------------------------------------------------------------------
extern "C" void kernel_launch(void* const* d_in, const int* in_sizes, int n_in,
                              void* d_out, int out_size, void* d_ws, size_t ws_size,
                              hipStream_t stream) {
  const float* x  = (const float*)d_in[0];
  const float* W1 = (const float*)d_in[1];
  const float* b1 = (const float*)d_in[2];
  const float* W2 = (const float*)d_in[3];
  const float* b2 = (const float*)d_in[4];
  const float* G1 = (const float*)d_in[5];
  const float* g1 = (const float*)d_in[6];
  const float* G2 = (const float*)d_in[7];
  const float* g2 = (const float*)d_in[8];
  const float* G3 = (const float*)d_in[9];
  const float* g3 = (const float*)d_in[10];

  float* y = (float*)d_out;                       // [N, O]
  float* pdense = y + (size_t)N_ * O_;            // [N, E]

  char* w = (char*)d_ws;
  auto alloc = [&](size_t bytes) -> char* {
    char* p = w;
    w += (bytes + 255) & ~(size_t)255;
    return p;
  };
  f16* xh  = (f16*)alloc((size_t)N_ * D_ * 2);
  f16* xl  = (f16*)alloc((size_t)N_ * D_ * 2);
  f16* G1h = (f16*)alloc((size_t)D_ * H_ * 2);    // [4096][1024]
  f16* G1l = (f16*)alloc((size_t)D_ * H_ * 2);
  f16* G2h = (f16*)alloc((size_t)H_ * D_ * 2);    // [1024][4096]
  f16* G2l = (f16*)alloc((size_t)H_ * D_ * 2);
  f16* W1t = (f16*)alloc((size_t)E_ * D_ * H_ * 2);  // [8][4096][1024]
  f16* W2t = (f16*)alloc((size_t)E_ * H_ * O_ * 2);  // [8][1024][4096]
  f16* h1h = (f16*)alloc((size_t)N_ * H_ * 2);       // reused as out_slots (f32) later
  f16* h1l = (f16*)alloc((size_t)N_ * H_ * 2);
  float* h2 = (float*)alloc((size_t)N_ * D_ * 4);
  float* logits = (float*)alloc((size_t)N_ * E_ * 4);
  int*   ti  = (int*)alloc((size_t)N_ * 2 * 4);
  float* tp  = (float*)alloc((size_t)N_ * 2 * 4);
  int*   cnt = (int*)alloc(64);
  int*   cur = (int*)alloc(64);
  int*   offs = (int*)alloc(64);
  int*   rowid = (int*)alloc((size_t)N_ * 2 * 4);
  int*   slotof = (int*)alloc((size_t)N_ * 2 * 4);
  f16*   hid = (f16*)alloc((size_t)N_ * 2 * H_ * 2);  // [16384][4096]

  // out_slots[16384][1024] f32 (64 MB) reuses h1h (dead after gate GEMM2)
  float* out_slots = (float*)h1h;

  hipMemsetAsync(cnt, 0, 64, stream);

  // conversions
  splitx_k<<<(N_ * D_) / 256, 256, 0, stream>>>(x, xh, xl, N_ * D_);
  tcast_k<true><<<dim3(H_ / 32, D_ / 32, 1), dim3(32, 8), 0, stream>>>(G1, G1h, G1l, D_, H_);
  tcast_k<true><<<dim3(D_ / 32, H_ / 32, 1), dim3(32, 8), 0, stream>>>(G2, G2h, G2l, H_, D_);
  tcast_k<false><<<dim3(H_ / 32, D_ / 32, E_), dim3(32, 8), 0, stream>>>(W1, W1t, nullptr, D_, H_);
  tcast_k<false><<<dim3(O_ / 32, H_ / 32, E_), dim3(32, 8), 0, stream>>>(W2, W2t, nullptr, H_, O_);

  // gate MLP (split f16, fp32-class)
  gemm_k<true, 0, 0><<<dim3(64, 32, 1), 256, 0, stream>>>(
      xh, xl, G1h, G1l, 0, g1, 0, h1h, h1l, N_, H_, D_,
      nullptr, nullptr, nullptr);
  gemm_k<true, 0, 1><<<dim3(64, 8, 1), 256, 0, stream>>>(
      h1h, h1l, G2h, G2l, 0, g2, 0, h2, nullptr, N_, D_, H_,
      nullptr, nullptr, nullptr);
  logits_k<<<N_ / 4, 256, 0, stream>>>(h2, G3, g3, logits);

  // routing
  top2_k<<<N_ / 256, 256, 0, stream>>>(logits, pdense, ti, tp, cnt);
  prefix_k<<<1, 64, 0, stream>>>(cnt, offs, cur);
  place_k<<<N_ / 256, 256, 0, stream>>>(ti, cur, rowid, slotof);

  // expert path (sparse top-2, plain f16)
  gemm_k<false, 1, 2><<<dim3(64, 32, E_), 256, 0, stream>>>(
      xh, nullptr, W1t, nullptr, (size_t)D_ * H_, b1, H_, hid, nullptr,
      N_, H_, D_, cnt, offs, rowid);
  gemm_k<false, 2, 3><<<dim3(64, 8, E_), 256, 0, stream>>>(
      hid, nullptr, W2t, nullptr, (size_t)H_ * O_, b2, O_, out_slots, nullptr,
      N_, O_, H_, cnt, offs, rowid);

  // weighted combine into y
  combine_k<<<N_, 256, 0, stream>>>(out_slots, slotof, tp, y);
}